// Round 1
// baseline (498.514 us; speedup 1.0000x reference)
//
#include <hip/hip_runtime.h>
#include <hip/hip_bf16.h>

#define GN 16384
#define GDIM 64

typedef __attribute__((ext_vector_type(8))) short bf16x8;
typedef __attribute__((ext_vector_type(4))) float f32x4;

__device__ __forceinline__ unsigned short f2bf(float x) {
    unsigned int u = __builtin_bit_cast(unsigned int, x);
    u += 0x7fffu + ((u >> 16) & 1u);          // round-to-nearest-even
    return (unsigned short)(u >> 16);
}

// ---------------- K1a: per-feature partial sums of h (256 blocks x 64 rows) ----
__global__ void bn_partial(const float* __restrict__ h, float* __restrict__ ps,
                           float* __restrict__ pq) {
    int b = blockIdx.x, t = threadIdx.x;
    int col = t & 63, wr = t >> 6;            // 4 waves -> 4 row phases
    float s = 0.f, q = 0.f;
    int base = b * 64;
    for (int rep = 0; rep < 16; ++rep) {
        int row = base + wr + rep * 4;
        float v = h[row * GDIM + col];
        s += v; q += v * v;
    }
    __shared__ float ls[4][64], lq[4][64];
    ls[wr][col] = s; lq[wr][col] = q;
    __syncthreads();
    if (t < 64) {
        ps[b * 64 + t] = ls[0][t] + ls[1][t] + ls[2][t] + ls[3][t];
        pq[b * 64 + t] = lq[0][t] + lq[1][t] + lq[2][t] + lq[3][t];
    }
}

// ---------------- K1b: finalize BN stats, fold into W' and b' ------------------
__global__ void bn_finalize(const float* __restrict__ ps, const float* __restrict__ pq,
                            const float* __restrict__ W, const float* __restrict__ bvec,
                            const float* __restrict__ gamma, const float* __restrict__ beta,
                            float* __restrict__ Wp, float* __restrict__ bp) {
    int t = threadIdx.x;
    __shared__ float s_s[64], s_t2[64];
    if (t < 64) {
        float S = 0.f, Q = 0.f;
        for (int b = 0; b < 256; ++b) { S += ps[b * 64 + t]; Q += pq[b * 64 + t]; }
        float mean = S * (1.0f / 16384.0f);
        float var  = Q * (1.0f / 16384.0f) - mean * mean;
        float sc   = gamma[t] * rsqrtf(var + 1e-5f);
        s_s[t]  = sc;
        s_t2[t] = beta[t] - mean * sc;
    }
    __syncthreads();
    for (int k = 0; k < 16; ++k) {            // Wp[o][c] = s[c]*W[o][c]
        int idx = t + k * 256;
        Wp[idx] = s_s[idx & 63] * W[idx];
    }
    if (t < 64) {
        float acc = bvec[t];
        for (int c = 0; c < 64; ++c) acc += s_t2[c] * W[t * 64 + c];
        bp[t] = acc;
    }
}

// ---------------- K2: hp = h @ W'^T + b'   (1024 blocks x 16 rows) -------------
__global__ void linear_hp(const float* __restrict__ h, const float* __restrict__ Wp,
                          const float* __restrict__ bpr, float* __restrict__ hp) {
    __shared__ float lw[64][65];
    __shared__ float lh[16][65];
    int t = threadIdx.x;
    int rb = blockIdx.x * 16;
    for (int k = 0; k < 16; ++k) {
        int idx = t + k * 256;
        lw[idx >> 6][idx & 63] = Wp[idx];
    }
    for (int k = 0; k < 4; ++k) {
        int idx = t + k * 256;                // 1024 elems = 16 rows x 64
        lh[idx >> 6][idx & 63] = h[rb * GDIM + idx];
    }
    __syncthreads();
    int o = t & 63, rg = t >> 6;              // rg = wave id (broadcast LDS reads)
    float a0 = 0.f, a1 = 0.f, a2 = 0.f, a3 = 0.f;
    for (int c = 0; c < 64; ++c) {
        float wv = lw[o][c];
        a0 += lh[rg][c]      * wv;
        a1 += lh[rg + 4][c]  * wv;
        a2 += lh[rg + 8][c]  * wv;
        a3 += lh[rg + 12][c] * wv;
    }
    float bb = bpr[o];
    hp[(rb + rg) * GDIM + o]      = a0 + bb;
    hp[(rb + rg + 4) * GDIM + o]  = a1 + bb;
    hp[(rb + rg + 8) * GDIM + o]  = a2 + bb;
    hp[(rb + rg + 12) * GDIM + o] = a3 + bb;
}

// ---------------- K3: dinv[i] = rsqrt(1 + sum_j g[i,j])  (block per row) -------
__global__ void rowsum_dinv(const float* __restrict__ g, float* __restrict__ dinv) {
    int row = blockIdx.x, t = threadIdx.x;
    const float4* grow = (const float4*)(g + (size_t)row * GN);
    float s = 0.f;
    for (int k = 0; k < 16; ++k) {
        float4 v = grow[t + k * 256];
        s += (v.x + v.y) + (v.z + v.w);
    }
    for (int off = 32; off; off >>= 1) s += __shfl_down(s, off, 64);
    __shared__ float wsum[4];
    if ((t & 63) == 0) wsum[t >> 6] = s;
    __syncthreads();
    if (t == 0) {
        float tot = (wsum[0] + wsum[1]) + (wsum[2] + wsum[3]) + 1.0f;
        dinv[row] = rsqrtf(tot);
    }
}

// ---------------- K4: hsT[o][j] = bf16(dinv[j]*hp[j][o])  (transposed B) -------
__global__ void make_hsT(const float* __restrict__ hp, const float* __restrict__ dinv,
                         unsigned short* __restrict__ hsT) {
    __shared__ float tile[64][65];
    int t = threadIdx.x;
    int jb = blockIdx.x * 64;
    int o = t & 63, jg = t >> 6;
    for (int k = 0; k < 16; ++k) {
        int j = jg + k * 4;
        tile[j][o] = hp[(jb + j) * GDIM + o] * dinv[jb + j];
    }
    __syncthreads();
    int oo = t >> 2, q = t & 3;
    for (int k = 0; k < 16; ++k) {
        int j = q * 16 + k;
        hsT[(size_t)oo * GN + jb + j] = f2bf(tile[j][oo]);
    }
}

// ---------------- K5: out = leaky(dinv_i*(g@hsT + dinv_i*hp))  -----------------
// 512 blocks x 32 rows; 4 waves split K (stride 128); MFMA 16x16x32 bf16.
__global__ void __launch_bounds__(256, 2) spmm_main(
    const float* __restrict__ g, const unsigned short* __restrict__ hsT,
    const float* __restrict__ hp, const float* __restrict__ dinv,
    float* __restrict__ out)
{
    int t = threadIdx.x;
    int lane = t & 63;
    int w = t >> 6;
    int rb = blockIdx.x * 32;
    int l15 = lane & 15;
    int kg = lane >> 4;                       // k-octet selector

    f32x4 acc[2][4];
    #pragma unroll
    for (int m = 0; m < 2; ++m)
        #pragma unroll
        for (int n = 0; n < 4; ++n)
            #pragma unroll
            for (int r = 0; r < 4; ++r) acc[m][n][r] = 0.f;

    for (int jb = w * 32; jb < GN; jb += 128) {
        bf16x8 afr[2];
        #pragma unroll
        for (int m = 0; m < 2; ++m) {
            const float* ap = g + (size_t)(rb + m * 16 + l15) * GN + jb + kg * 8;
            f32x4 x0 = *(const f32x4*)ap;
            f32x4 x1 = *(const f32x4*)(ap + 4);
            bf16x8 f;
            f[0] = (short)f2bf(x0[0]); f[1] = (short)f2bf(x0[1]);
            f[2] = (short)f2bf(x0[2]); f[3] = (short)f2bf(x0[3]);
            f[4] = (short)f2bf(x1[0]); f[5] = (short)f2bf(x1[1]);
            f[6] = (short)f2bf(x1[2]); f[7] = (short)f2bf(x1[3]);
            afr[m] = f;
        }
        #pragma unroll
        for (int n = 0; n < 4; ++n) {
            const unsigned short* bptr = hsT + (size_t)(n * 16 + l15) * GN + jb + kg * 8;
            bf16x8 bfr = *(const bf16x8*)bptr;
            acc[0][n] = __builtin_amdgcn_mfma_f32_16x16x32_bf16(afr[0], bfr, acc[0][n], 0, 0, 0);
            acc[1][n] = __builtin_amdgcn_mfma_f32_16x16x32_bf16(afr[1], bfr, acc[1][n], 0, 0, 0);
        }
    }

    __shared__ float red[4][32][64];
    #pragma unroll
    for (int m = 0; m < 2; ++m)
        #pragma unroll
        for (int n = 0; n < 4; ++n)
            #pragma unroll
            for (int r = 0; r < 4; ++r) {
                int row = m * 16 + kg * 4 + r;          // C/D map: col=lane&15, row=4*(lane>>4)+r
                int col = n * 16 + l15;
                red[w][row][col] = acc[m][n][r];
            }
    __syncthreads();

    for (int k = 0; k < 8; ++k) {
        int idx = t + k * 256;
        int row = idx >> 6, col = idx & 63;
        float s = (red[0][row][col] + red[1][row][col]) +
                  (red[2][row][col] + red[3][row][col]);
        int i = rb + row;
        float di = dinv[i];
        float v = di * (s + di * hp[i * GDIM + col]);
        out[i * GDIM + col] = (v >= 0.f) ? v : 0.01f * v;
    }
}

extern "C" void kernel_launch(void* const* d_in, const int* in_sizes, int n_in,
                              void* d_out, int out_size, void* d_ws, size_t ws_size,
                              hipStream_t stream) {
    const float* g     = (const float*)d_in[0];
    const float* h     = (const float*)d_in[1];
    const float* W     = (const float*)d_in[2];
    const float* b     = (const float*)d_in[3];
    const float* gamma = (const float*)d_in[4];
    const float* beta  = (const float*)d_in[5];
    float* out = (float*)d_out;

    float* ws   = (float*)d_ws;
    float* ps   = ws;                       // 16384
    float* pq   = ws + 16384;               // 16384
    float* Wp   = ws + 32768;               // 4096
    float* bp   = ws + 36864;               // 64
    float* dinv = ws + 36928;               // 16384
    float* hp   = ws + 53312;               // 1048576
    unsigned short* hsT = (unsigned short*)(ws + 53312 + 1048576); // 2 MB

    bn_partial  <<<256,   256, 0, stream>>>(h, ps, pq);
    bn_finalize <<<1,     256, 0, stream>>>(ps, pq, W, b, gamma, beta, Wp, bp);
    linear_hp   <<<1024,  256, 0, stream>>>(h, Wp, bp, hp);
    rowsum_dinv <<<16384, 256, 0, stream>>>(g, dinv);
    make_hsT    <<<256,   256, 0, stream>>>(hp, dinv, hsT);
    spmm_main   <<<512,   256, 0, stream>>>(g, hsT, hp, dinv, out);
}